// Round 14
// baseline (281.730 us; speedup 1.0000x reference)
//
#include <hip/hip_runtime.h>
#include <math.h>

#define NODES 100000
#define EDGES 1600000
#define NBUCK 196     // ceil(NODES/512) dst-range buckets (512 nodes each)
#define BCAP2 12288   // capacity per bucket (mean 8163, +45 sigma slack)
#define EPB 4096      // edges per binning block

typedef __attribute__((ext_vector_type(8))) short short8;
typedef __attribute__((ext_vector_type(4))) short shortx4;
typedef __attribute__((ext_vector_type(4))) float floatx4;
typedef __attribute__((ext_vector_type(4))) unsigned uv4;
typedef __attribute__((ext_vector_type(4))) int intx4;

// group-of-8 reduction (xor 4,2,1 stays inside an aligned 8-lane group)
__device__ __forceinline__ float gsum8(float x) {
#pragma unroll
  for (int o = 4; o > 0; o >>= 1) x += __shfl_xor(x, o, 64);
  return x;
}

// bf16 <-> fp32 (RNE), no dependence on __hip_bfloat16 internals.
__device__ __forceinline__ short f2bf(float f) {
  union { float f; unsigned u; } v;
  v.f = f;
  unsigned r = 0x7fffu + ((v.u >> 16) & 1u);
  return (short)((v.u + r) >> 16);
}
__device__ __forceinline__ float bflo(unsigned p) {
  union { unsigned u; float f; } v; v.u = p << 16; return v.f;
}
__device__ __forceinline__ float bfhi(unsigned p) {
  union { unsigned u; float f; } v; v.u = p & 0xffff0000u; return v.f;
}

// ---------- phase A: two-pass LDS binning, int4 loads, per-wave histograms ----------
// record = src (17b) | (dst & 511) << 17
__global__ __launch_bounds__(256) void k_bin2(const intx4* __restrict__ src4,
                                              const intx4* __restrict__ dst4,
                                              int* __restrict__ bins,
                                              int* __restrict__ gcur) {
  __shared__ int cnt[4][NBUCK], wb[4][NBUCK], lcur[4][NBUCK];
  int t = threadIdx.x, w = t >> 6;
  for (int i = t; i < NBUCK; i += 256) { cnt[0][i] = 0; cnt[1][i] = 0; cnt[2][i] = 0; cnt[3][i] = 0; }
  __syncthreads();
  int base4 = blockIdx.x * (EPB / 4);
  intx4 sv[4], dv[4];
  bool val[4];
#pragma unroll
  for (int k = 0; k < 4; ++k) {
    int i4 = base4 + k * 256 + t;           // coalesced 16B loads
    val[k] = (i4 < EDGES / 4);
    if (val[k]) {
      sv[k] = src4[i4];
      dv[k] = dst4[i4];
#pragma unroll
      for (int j = 0; j < 4; ++j) atomicAdd(&cnt[w][dv[k][j] >> 9], 1);  // wave-local
    }
  }
  __syncthreads();
  for (int i = t; i < NBUCK; i += 256) {
    int c0 = cnt[0][i], c1 = cnt[1][i], c2 = cnt[2][i], c3 = cnt[3][i];
    int tot = c0 + c1 + c2 + c3;
    int g = tot ? atomicAdd(&gcur[i], tot) : 0;  // ONE global atomic per (block,bucket)
    wb[0][i] = g; wb[1][i] = g + c0; wb[2][i] = g + c0 + c1; wb[3][i] = g + c0 + c1 + c2;
    lcur[0][i] = 0; lcur[1][i] = 0; lcur[2][i] = 0; lcur[3][i] = 0;
  }
  __syncthreads();
#pragma unroll
  for (int k = 0; k < 4; ++k) {
    if (val[k]) {
#pragma unroll
      for (int j = 0; j < 4; ++j) {
        int d = dv[k][j], bk = d >> 9;
        int lp = atomicAdd(&lcur[w][bk], 1);     // wave-local cursor
        int pos = wb[w][bk] + lp;
        if (pos < BCAP2) bins[bk * BCAP2 + pos] = sv[k][j] | ((d & 511) << 17);
      }
    }
  }
}

// ---------- fused: bucket scan + per-bucket histogram + rowptr/dinv + csr fill ----------
__global__ __launch_bounds__(256) void k_fillb2(const int* __restrict__ bins,
                                                const int* __restrict__ gcur,
                                                int* __restrict__ rowptr,
                                                float* __restrict__ dinv,
                                                int* __restrict__ csr) {
  __shared__ int bsm[256];
  __shared__ int cnt[512], cur[512], wtot[4];
  int b = blockIdx.x, t = threadIdx.x;
  int v = 0;
  if (t < NBUCK) { v = gcur[t]; if (v > BCAP2) v = BCAP2; }
  bsm[t] = v;
  cnt[t] = 0; cnt[t + 256] = 0;
  __syncthreads();
  for (int o = 1; o < 256; o <<= 1) {
    int u = (t >= o) ? bsm[t - o] : 0;
    __syncthreads();
    bsm[t] += u;
    __syncthreads();
  }
  if (b == 0 && t == NBUCK - 1) rowptr[NODES] = bsm[t];
  int cb = gcur[b]; if (cb > BCAP2) cb = BCAP2;
  int base = bsm[b] - cb;
  const int* bp = &bins[(size_t)b * BCAP2];
  for (int i = t; i < cb; i += 256)
    atomicAdd(&cnt[(bp[i] >> 17) & 511], 1);
  __syncthreads();
  int a0 = cnt[2 * t], a1 = cnt[2 * t + 1];
  int s = a0 + a1;
  int lane = t & 63, w = t >> 6;
  int inc = s;
#pragma unroll
  for (int o = 1; o < 64; o <<= 1) {
    int u = __shfl_up(inc, o, 64);
    if (lane >= o) inc += u;
  }
  if (lane == 63) wtot[w] = inc;
  __syncthreads();
  int wpre = 0;
  for (int ww = 0; ww < w; ++ww) wpre += wtot[ww];
  int r0 = base + wpre + inc - s;
  int r1 = r0 + a0;
  int n0 = b * 512 + 2 * t, n1 = n0 + 1;
  if (n0 < NODES) { rowptr[n0] = r0; dinv[n0] = rsqrtf((float)a0 + 1.0f); }
  if (n1 < NODES) { rowptr[n1] = r1; dinv[n1] = rsqrtf((float)a1 + 1.0f); }
  cur[2 * t] = r0; cur[2 * t + 1] = r1;
  __syncthreads();
  for (int i = t; i < cb; i += 256) {
    int pk = bp[i];
    int p = atomicAdd(&cur[(pk >> 17) & 511], 1);
    csr[p] = pk & 0x1FFFF;
  }
}

// ---------- GEMM (fp32 acts): [N,K] fp32 @ [K,64] -> hs = (x@W)*dinv[row], bf16 ----------
// x tile staged to LDS via coalesced float4 loads; fragments read from LDS.
template <int K>
__global__ __launch_bounds__(256) void k_gemm_f32(const float* __restrict__ x,
                                                  const float* __restrict__ W,
                                                  const float* __restrict__ dinv,
                                                  short* __restrict__ hs) {
  constexpr int KP = K + 8;
  __shared__ __align__(16) short wt[64 * KP];
  __shared__ __align__(16) short xt[64 * KP];
  int t = threadIdx.x;
  for (int idx = t; idx < K * 64; idx += 256) {
    int k = idx >> 6, n = idx & 63;
    wt[n * KP + k] = f2bf(W[idx]);  // W^T staged as bf16
  }
  int blk0 = blockIdx.x * 64;       // 64 rows per block
  {
    const floatx4* x4 = (const floatx4*)(x + (size_t)blk0 * K);
    constexpr int C4 = K / 4;       // float4s per row
    for (int i = t; i < 64 * C4; i += 256) {   // fully coalesced
      int row = i / C4, c4 = i % C4;
      shortx4 o = {0, 0, 0, 0};
      if (blk0 + row < NODES) {
        floatx4 vv = x4[i];
#pragma unroll
        for (int j = 0; j < 4; ++j) o[j] = f2bf(vv[j]);
      }
      *reinterpret_cast<shortx4*>(&xt[row * KP + c4 * 4]) = o;
    }
  }
  __syncthreads();
  int wid = t >> 6, lane = t & 63;
  int tile = blockIdx.x * 4 + wid;
  if (tile * 16 >= NODES) return;
  int m = lane & 15, q = lane >> 4;

  short8 bfr[4][K / 32];
#pragma unroll
  for (int ct = 0; ct < 4; ++ct)
#pragma unroll
    for (int ks = 0; ks < K / 32; ++ks)
      bfr[ct][ks] = *reinterpret_cast<const short8*>(&wt[(ct * 16 + m) * KP + ks * 32 + q * 8]);

  floatx4 acc[4];
#pragma unroll
  for (int ct = 0; ct < 4; ++ct) acc[ct] = {0.f, 0.f, 0.f, 0.f};
  int r0 = tile * 16;
#pragma unroll
  for (int ks = 0; ks < K / 32; ++ks) {
    short8 af = *reinterpret_cast<const short8*>(&xt[(wid * 16 + m) * KP + ks * 32 + q * 8]);
#pragma unroll
    for (int ct = 0; ct < 4; ++ct)
      acc[ct] = __builtin_amdgcn_mfma_f32_16x16x32_bf16(af, bfr[ct][ks], acc[ct], 0, 0, 0);
  }
  // C/D: col = lane&15, row = (lane>>4)*4 + reg   [measured m89/m91]
  float dv[4];
#pragma unroll
  for (int r = 0; r < 4; ++r) dv[r] = dinv[r0 + q * 4 + r];
#pragma unroll
  for (int ct = 0; ct < 4; ++ct)
#pragma unroll
    for (int r = 0; r < 4; ++r) {
      int row = r0 + q * 4 + r, col = ct * 16 + m;
      hs[row * 64 + col] = f2bf(acc[ct][r] * dv[r]);
    }
}

// ---------- fused aggregate + bias + LN + GELU + next-layer GEMM ----------
// reads hs (dinv-prescaled), writes hsn = dinv ⊙ (u @ W)  [row-scale commute]
__global__ __launch_bounds__(256) void k_aggg(const short* __restrict__ hs,
                                              const float* __restrict__ dinv,
                                              const int* __restrict__ rowptr,
                                              const int* __restrict__ csr,
                                              const float* __restrict__ bias,
                                              const float* __restrict__ gam,
                                              const float* __restrict__ bet,
                                              const float* __restrict__ W,
                                              short* __restrict__ hsn) {
  __shared__ __align__(16) short wt[64 * 72];  // W^T bf16
  __shared__ __align__(16) short ut[32 * 72];  // (dinv*u) tile bf16
  int t = threadIdx.x;
  for (int idx = t; idx < 4096; idx += 256) {
    int k = idx >> 6, n = idx & 63;
    wt[n * 72 + k] = f2bf(W[idx]);
  }
  const uv4* hsv = (const uv4*)hs;
  int lane = t & 63, wid = t >> 6;
  int g = lane >> 3, q = lane & 7;
  int nb0 = blockIdx.x * 32;
  int r = wid * 8 + g;
  int n = nb0 + r;
  int e0 = rowptr[n], e1 = rowptr[n + 1];
  float dn = dinv[n];
  uv4 sv = hsv[(size_t)n * 8 + q];
  float acc[8];
#pragma unroll
  for (int w = 0; w < 4; ++w) { acc[2 * w] = bflo(sv[w]); acc[2 * w + 1] = bfhi(sv[w]); }

  int srcb = lane & 0x38;
  for (int base = e0; base < e1; base += 8) {
    int cnt = e1 - base;
    if (cnt > 8) cnt = 8;
    int a = base + (q < cnt ? q : 0);
    int sidx = csr[a];
    int s[8];
#pragma unroll
    for (int j = 0; j < 8; ++j) s[j] = __shfl(sidx, srcb | j, 64);
    uv4 v[8];
#pragma unroll
    for (int j = 0; j < 8; ++j) v[j] = hsv[(size_t)s[j] * 8 + q];
    if (cnt == 8) {
#pragma unroll
      for (int j = 0; j < 8; ++j)
#pragma unroll
        for (int w = 0; w < 4; ++w) { acc[2 * w] += bflo(v[j][w]); acc[2 * w + 1] += bfhi(v[j][w]); }
    } else {
#pragma unroll
      for (int j = 0; j < 8; ++j)
        if (j < cnt)
#pragma unroll
          for (int w = 0; w < 4; ++w) { acc[2 * w] += bflo(v[j][w]); acc[2 * w + 1] += bfhi(v[j][w]); }
    }
  }

  const floatx4* bi4 = (const floatx4*)bias;
  floatx4 b0 = bi4[q * 2], b1 = bi4[q * 2 + 1];
#pragma unroll
  for (int f = 0; f < 4; ++f) { acc[f] = acc[f] * dn + b0[f]; acc[f + 4] = acc[f + 4] * dn + b1[f]; }

  float lsum = 0.f;
#pragma unroll
  for (int f = 0; f < 8; ++f) lsum += acc[f];
  float mu = gsum8(lsum) * (1.0f / 64.0f);
  float d[8], lvar = 0.f;
#pragma unroll
  for (int f = 0; f < 8; ++f) { d[f] = acc[f] - mu; lvar += d[f] * d[f]; }
  float rs = rsqrtf(gsum8(lvar) * (1.0f / 64.0f) + 1e-5f);
  const floatx4* gm4 = (const floatx4*)gam;
  const floatx4* bt4 = (const floatx4*)bet;
  floatx4 g0 = gm4[q * 2], g1 = gm4[q * 2 + 1];
  floatx4 t0 = bt4[q * 2], t1 = bt4[q * 2 + 1];
  short8 us;
#pragma unroll
  for (int f = 0; f < 8; ++f) {
    float gv = (f < 4) ? g0[f] : g1[f - 4];
    float tv = (f < 4) ? t0[f] : t1[f - 4];
    float vv = d[f] * rs * gv + tv;
    float u = 0.5f * vv * (1.0f + erff(vv * 0.70710678118654752f));  // exact GELU
    us[f] = f2bf(u * dn);                   // prescale for next layer (commute)
  }
  *reinterpret_cast<short8*>(&ut[r * 72 + q * 8]) = us;
  __syncthreads();

  // in-block GEMM: 32x64 tile @ W (64x64) -> hsn rows nb0..nb0+31
  int m = lane & 15, q2 = lane >> 4;
  int tile = wid >> 1, cb = (wid & 1) * 2;
  short8 bfr[2][2];
#pragma unroll
  for (int ct = 0; ct < 2; ++ct)
#pragma unroll
    for (int ks = 0; ks < 2; ++ks)
      bfr[ct][ks] = *reinterpret_cast<const short8*>(&wt[((cb + ct) * 16 + m) * 72 + ks * 32 + q2 * 8]);
  floatx4 ac[2];
#pragma unroll
  for (int ct = 0; ct < 2; ++ct) ac[ct] = {0.f, 0.f, 0.f, 0.f};
#pragma unroll
  for (int ks = 0; ks < 2; ++ks) {
    short8 af = *reinterpret_cast<const short8*>(&ut[(tile * 16 + m) * 72 + ks * 32 + q2 * 8]);
#pragma unroll
    for (int ct = 0; ct < 2; ++ct)
      ac[ct] = __builtin_amdgcn_mfma_f32_16x16x32_bf16(af, bfr[ct][ks], ac[ct], 0, 0, 0);
  }
#pragma unroll
  for (int ct = 0; ct < 2; ++ct)
#pragma unroll
    for (int rr = 0; rr < 4; ++rr) {
      int row = nb0 + tile * 16 + q2 * 4 + rr, col = (cb + ct) * 16 + m;
      hsn[row * 64 + col] = f2bf(ac[ct][rr]);
    }
}

// ---------- final layer: aggregate + bias + LN + GELU + head ----------
__global__ __launch_bounds__(256) void k_agg_fin(const short* __restrict__ hs,
                                                 const float* __restrict__ dinv,
                                                 const int* __restrict__ rowptr,
                                                 const int* __restrict__ csr,
                                                 const float* __restrict__ bias,
                                                 const float* __restrict__ gam,
                                                 const float* __restrict__ bet,
                                                 const float* __restrict__ Wh,
                                                 const float* __restrict__ bh,
                                                 float* __restrict__ out) {
  const uv4* hsv = (const uv4*)hs;
  int lane = threadIdx.x & 63, wid = threadIdx.x >> 6;
  int g = lane >> 3, q = lane & 7;
  int n = blockIdx.x * 32 + wid * 8 + g;
  int e0 = rowptr[n], e1 = rowptr[n + 1];
  float dn = dinv[n];
  uv4 sv = hsv[(size_t)n * 8 + q];
  float acc[8];
#pragma unroll
  for (int w = 0; w < 4; ++w) { acc[2 * w] = bflo(sv[w]); acc[2 * w + 1] = bfhi(sv[w]); }
  int srcb = lane & 0x38;
  for (int base = e0; base < e1; base += 8) {
    int cnt = e1 - base;
    if (cnt > 8) cnt = 8;
    int a = base + (q < cnt ? q : 0);
    int sidx = csr[a];
    int s[8];
#pragma unroll
    for (int j = 0; j < 8; ++j) s[j] = __shfl(sidx, srcb | j, 64);
    uv4 v[8];
#pragma unroll
    for (int j = 0; j < 8; ++j) v[j] = hsv[(size_t)s[j] * 8 + q];
    if (cnt == 8) {
#pragma unroll
      for (int j = 0; j < 8; ++j)
#pragma unroll
        for (int w = 0; w < 4; ++w) { acc[2 * w] += bflo(v[j][w]); acc[2 * w + 1] += bfhi(v[j][w]); }
    } else {
#pragma unroll
      for (int j = 0; j < 8; ++j)
        if (j < cnt)
#pragma unroll
          for (int w = 0; w < 4; ++w) { acc[2 * w] += bflo(v[j][w]); acc[2 * w + 1] += bfhi(v[j][w]); }
    }
  }
  const floatx4* bi4 = (const floatx4*)bias;
  floatx4 b0 = bi4[q * 2], b1 = bi4[q * 2 + 1];
#pragma unroll
  for (int f = 0; f < 4; ++f) { acc[f] = acc[f] * dn + b0[f]; acc[f + 4] = acc[f + 4] * dn + b1[f]; }
  float lsum = 0.f;
#pragma unroll
  for (int f = 0; f < 8; ++f) lsum += acc[f];
  float mu = gsum8(lsum) * (1.0f / 64.0f);
  float d[8], lvar = 0.f;
#pragma unroll
  for (int f = 0; f < 8; ++f) { d[f] = acc[f] - mu; lvar += d[f] * d[f]; }
  float rs = rsqrtf(gsum8(lvar) * (1.0f / 64.0f) + 1e-5f);
  const floatx4* gm4 = (const floatx4*)gam;
  const floatx4* bt4 = (const floatx4*)bet;
  floatx4 g0 = gm4[q * 2], g1 = gm4[q * 2 + 1];
  floatx4 t0 = bt4[q * 2], t1 = bt4[q * 2 + 1];
  const floatx4* wh4 = (const floatx4*)Wh;
  floatx4 w0 = wh4[q * 2], w1 = wh4[q * 2 + 1];
  float lp = 0.f;
#pragma unroll
  for (int f = 0; f < 8; ++f) {
    float gv = (f < 4) ? g0[f] : g1[f - 4];
    float tv = (f < 4) ? t0[f] : t1[f - 4];
    float wv = (f < 4) ? w0[f] : w1[f - 4];
    float vv = d[f] * rs * gv + tv;
    float u = 0.5f * vv * (1.0f + erff(vv * 0.70710678118654752f));
    lp += u * wv;
  }
  float p = gsum8(lp);
  if (q == 0) out[n] = p + bh[0];
}

extern "C" void kernel_launch(void* const* d_in, const int* in_sizes, int n_in,
                              void* d_out, int out_size, void* d_ws, size_t ws_size,
                              hipStream_t stream) {
  const float* x  = (const float*)d_in[0];
  const int* ei   = (const int*)d_in[1];
  const float* W1 = (const float*)d_in[2];
  const float* b1 = (const float*)d_in[3];
  const float* g1 = (const float*)d_in[4];
  const float* be1= (const float*)d_in[5];
  const float* W2 = (const float*)d_in[6];
  const float* b2 = (const float*)d_in[7];
  const float* g2 = (const float*)d_in[8];
  const float* be2= (const float*)d_in[9];
  const float* W3 = (const float*)d_in[10];
  const float* b3 = (const float*)d_in[11];
  const float* g3 = (const float*)d_in[12];
  const float* be3= (const float*)d_in[13];
  const float* Wh = (const float*)d_in[14];
  const float* bh = (const float*)d_in[15];
  const intx4* src4 = (const intx4*)ei;
  const intx4* dst4 = (const intx4*)(ei + EDGES);

  char* ws = (char*)d_ws;
  size_t off = 0;
  auto take = [&](size_t bytes) {
    char* p = ws + off;
    off = (off + bytes + 255) & ~(size_t)255;
    return p;
  };
  float* dinv = (float*)take((size_t)NODES * 4);
  int* rowptr = (int*)take((size_t)(NODES + 1) * 4);
  int* csr    = (int*)take((size_t)EDGES * 4);
  short* hs_a = (short*)take((size_t)NODES * 64 * 2);   // 12.8 MB
  short* hs_b = (short*)take((size_t)NODES * 64 * 2);   // 12.8 MB
  // bins/gcur alias hs_a/hs_b: consumed by fillb2 before any GEMM writes hs.
  int* bins   = (int*)hs_a;                              // NBUCK*BCAP2*4 = 9.63 MB
  int* gcur   = (int*)hs_b;                              // NBUCK*4 = 784 B

  (void)hipMemsetAsync(gcur, 0, (size_t)NBUCK * 4, stream);
  k_bin2<<<(EDGES / 4 + 1023) / 1024, 256, 0, stream>>>(src4, dst4, bins, gcur);
  k_fillb2<<<NBUCK, 256, 0, stream>>>(bins, gcur, rowptr, dinv, csr);

  int gemm_grid = (NODES + 63) / 64;  // 1563 blocks x 4 waves
  k_gemm_f32<128><<<gemm_grid, 256, 0, stream>>>(x, W1, dinv, hs_a);
  k_aggg<<<NODES / 32, 256, 0, stream>>>(hs_a, dinv, rowptr, csr, b1, g1, be1, W2, hs_b);
  k_aggg<<<NODES / 32, 256, 0, stream>>>(hs_b, dinv, rowptr, csr, b2, g2, be2, W3, hs_a);
  k_agg_fin<<<NODES / 32, 256, 0, stream>>>(hs_a, dinv, rowptr, csr, b3, g3, be3, Wh, bh, (float*)d_out);
}